// Round 4
// baseline (1342.786 us; speedup 1.0000x reference)
//
#include <hip/hip_runtime.h>
#include <hip/hip_bf16.h>
#include <math.h>

#define B_ 4
#define S_ 2048
#define H_ 1024
#define KC 128
#define EPSF 1e-8f

// ------------------------------------------------------------------
// Kernel 1: top-K candidate selection (one block per (batch, class)).
// ------------------------------------------------------------------
__global__ __launch_bounds__(256) void topk_kernel(
    const float* __restrict__ logits,   // [B,S,3]
    const int*   __restrict__ mask,     // [B,S]
    int* __restrict__ key_idx,          // [B,K]
    int* __restrict__ val_idx)          // [B,K]
{
    __shared__ float conf[S_];
    __shared__ float bval[256];
    __shared__ int   bidx[256];
    __shared__ unsigned int taken[S_ / 32];

    const int tid = threadIdx.x;
    const int blk = blockIdx.x;          // 0..7
    const int b   = blk >> 1;
    const int cls = (blk & 1) ? 2 : 1;
    int* idx_out = (blk & 1) ? (val_idx + b * KC) : (key_idx + b * KC);

    for (int s = tid; s < S_; s += 256) {
        float l0 = logits[(b * S_ + s) * 3 + 0];
        float l1 = logits[(b * S_ + s) * 3 + 1];
        float l2 = logits[(b * S_ + s) * 3 + 2];
        int pred = 0; float bl = l0;
        if (l1 > bl) { bl = l1; pred = 1; }
        if (l2 > bl) { bl = l2; pred = 2; }
        float c = -1.0f;                 // sentinel below any valid conf (>=1/3)
        if (pred == cls && mask[b * S_ + s] == 1) {
            double m = (double)bl;
            double e0 = exp((double)l0 - m);
            double e1 = exp((double)l1 - m);
            double e2 = exp((double)l2 - m);
            c = (float)(((cls == 1) ? e1 : e2) / (e0 + e1 + e2));
        }
        conf[s] = c;
    }
    for (int i = tid; i < S_ / 32; i += 256) taken[i] = 0u;
    __syncthreads();

    for (int it = 0; it < KC; ++it) {
        float best = -2.0f; int bi = S_;
        for (int s = tid; s < S_; s += 256) {
            if ((taken[s >> 5] >> (s & 31)) & 1u) continue;
            float c = conf[s];
            if (c > best || (c == best && s < bi)) { best = c; bi = s; }
        }
        bval[tid] = best; bidx[tid] = bi;
        __syncthreads();
        for (int stride = 128; stride >= 1; stride >>= 1) {
            if (tid < stride) {
                float ov = bval[tid + stride]; int oi = bidx[tid + stride];
                if (ov > bval[tid] || (ov == bval[tid] && oi < bidx[tid])) {
                    bval[tid] = ov; bidx[tid] = oi;
                }
            }
            __syncthreads();
        }
        if (tid == 0) {
            int sel = bidx[0];
            idx_out[it] = sel;
            taken[sel >> 5] |= (1u << (sel & 31));
        }
        __syncthreads();
    }
}

// ------------------------------------------------------------------
// Kernel 2: per-batch C[128,H] = gather(A)[128,H] @ W[H,H] (+bias), f32.
// ------------------------------------------------------------------
#define BM 64
#define BN 64
#define BKc 16

__global__ __launch_bounds__(256) void gemm128_kernel(
    const float* __restrict__ Abase, // seq + b*S*H (gather) or krep (idx==null)
    const int*   __restrict__ idx,   // [128] or nullptr
    const float* __restrict__ W,     // [H,H] row-major
    const float* __restrict__ bias,  // [H] or nullptr
    float* __restrict__ Cout)        // [128,H]
{
    __shared__ float As[BM][BKc + 1];
    __shared__ float Bs[BKc][BN];
    const int tid = threadIdx.x;
    const int m0 = blockIdx.y * BM;
    const int n0 = blockIdx.x * BN;
    const int ty = tid >> 4, tx = tid & 15;
    float acc[4][4] = {};

    const int ar = tid >> 2, aq = (tid & 3) * 4;   // A tile: 64 x 16
    const int am = m0 + ar;
    const float* arow = idx ? (Abase + (size_t)idx[am] * H_)
                            : (Abase + (size_t)am * H_);
    const int br = tid >> 4, bq = (tid & 15) * 4;  // B tile: 16 x 64

    for (int h0 = 0; h0 < H_; h0 += BKc) {
        float4 av = *(const float4*)(arow + h0 + aq);
        As[ar][aq + 0] = av.x; As[ar][aq + 1] = av.y;
        As[ar][aq + 2] = av.z; As[ar][aq + 3] = av.w;
        float4 bv = *(const float4*)(W + (size_t)(h0 + br) * H_ + n0 + bq);
        *(float4*)&Bs[br][bq] = bv;
        __syncthreads();
        #pragma unroll
        for (int kk = 0; kk < BKc; ++kk) {
            float a_[4], b_[4];
            #pragma unroll
            for (int i = 0; i < 4; ++i) a_[i] = As[ty * 4 + i][kk];
            #pragma unroll
            for (int j = 0; j < 4; ++j) b_[j] = Bs[kk][tx * 4 + j];
            #pragma unroll
            for (int i = 0; i < 4; ++i)
                #pragma unroll
                for (int j = 0; j < 4; ++j) acc[i][j] += a_[i] * b_[j];
        }
        __syncthreads();
    }
    #pragma unroll
    for (int i = 0; i < 4; ++i) {
        int m = m0 + ty * 4 + i;
        #pragma unroll
        for (int j = 0; j < 4; ++j) {
            int n = n0 + tx * 4 + j;
            Cout[(size_t)m * H_ + n] = acc[i][j] + (bias ? bias[n] : 0.0f);
        }
    }
}

// ------------------------------------------------------------------
// Kernel 3 (per batch): biafF[k,v] = dot(kbt[k,:], vrep[v,:]) + bbil  (f32)
// ------------------------------------------------------------------
__global__ __launch_bounds__(256) void biaffine128_kernel(
    const float* __restrict__ kbt,   // [128,H]
    const float* __restrict__ vrep,  // [128,H]
    const float* __restrict__ bbil,  // scalar
    float* __restrict__ biafF)       // [128,128]
{
    __shared__ float As[BM][BKc + 1];
    __shared__ float Bs[BM][BKc + 1];
    const int tid = threadIdx.x;
    const int m0 = blockIdx.y * BM;
    const int n0 = blockIdx.x * BN;
    const int ty = tid >> 4, tx = tid & 15;
    float acc[4][4] = {};

    const int ar = tid >> 2, aq = (tid & 3) * 4;
    const float* arow = kbt  + (size_t)(m0 + ar) * H_;
    const float* brow = vrep + (size_t)(n0 + ar) * H_;

    for (int h0 = 0; h0 < H_; h0 += BKc) {
        float4 av = *(const float4*)(arow + h0 + aq);
        As[ar][aq + 0] = av.x; As[ar][aq + 1] = av.y;
        As[ar][aq + 2] = av.z; As[ar][aq + 3] = av.w;
        float4 bv = *(const float4*)(brow + h0 + aq);
        Bs[ar][aq + 0] = bv.x; Bs[ar][aq + 1] = bv.y;
        Bs[ar][aq + 2] = bv.z; Bs[ar][aq + 3] = bv.w;
        __syncthreads();
        #pragma unroll
        for (int kk = 0; kk < BKc; ++kk) {
            float a_[4], b_[4];
            #pragma unroll
            for (int i = 0; i < 4; ++i) a_[i] = As[ty * 4 + i][kk];
            #pragma unroll
            for (int j = 0; j < 4; ++j) b_[j] = Bs[tx * 4 + j][kk];
            #pragma unroll
            for (int i = 0; i < 4; ++i)
                #pragma unroll
                for (int j = 0; j < 4; ++j) acc[i][j] += a_[i] * b_[j];
        }
        __syncthreads();
    }
    float bb = *bbil;
    #pragma unroll
    for (int i = 0; i < 4; ++i) {
        int m = m0 + ty * 4 + i;
        #pragma unroll
        for (int j = 0; j < 4; ++j) {
            int n = n0 + tx * 4 + j;
            biafF[(size_t)m * KC + n] = acc[i][j] + bb;
        }
    }
}

// ------------------------------------------------------------------
// Kernel 4: spatial features + MLP(8->64->32) + final MLP(33->16->1).
// Reads f32 biaffine from sc[gid], overwrites with final f32 score.
// ------------------------------------------------------------------
__global__ __launch_bounds__(256) void fused_spatial_kernel(
    const float* __restrict__ bboxes,  // [B,S,4]
    const int* __restrict__ key_idx, const int* __restrict__ val_idx,
    const float* __restrict__ Ws1, const float* __restrict__ bs1,
    const float* __restrict__ Ws2, const float* __restrict__ bs2,
    const float* __restrict__ Wf1, const float* __restrict__ bf1,
    const float* __restrict__ Wf2, const float* __restrict__ bf2,
    float* sc)                          // [B,K,V] f32 (biaffine in, score out)
{
    __shared__ float sWs1[8 * 64];
    __shared__ float sbs1[64];
    __shared__ float sWs2[64 * 32];
    __shared__ float sbs2[32];
    __shared__ float sWf1[33 * 16];
    __shared__ float sbf1[16];
    __shared__ float sWf2[16];

    const int tid = threadIdx.x;
    for (int i = tid; i < 8 * 64;  i += 256) sWs1[i] = Ws1[i];
    for (int i = tid; i < 64;      i += 256) sbs1[i] = bs1[i];
    for (int i = tid; i < 64 * 32; i += 256) sWs2[i] = Ws2[i];
    for (int i = tid; i < 32;      i += 256) sbs2[i] = bs2[i];
    for (int i = tid; i < 33 * 16; i += 256) sWf1[i] = Wf1[i];
    for (int i = tid; i < 16;      i += 256) sbf1[i] = bf1[i];
    for (int i = tid; i < 16;      i += 256) sWf2[i] = Wf2[i];
    __syncthreads();

    const int gid = blockIdx.x * 256 + tid;   // < B*K*V = 65536
    const int b = gid >> 14;
    const int rem = gid & 16383;
    const int k = rem >> 7;
    const int v = rem & 127;

    const float* kb = bboxes + ((size_t)b * S_ + key_idx[b * KC + k]) * 4;
    const float* vb = bboxes + ((size_t)b * S_ + val_idx[b * KC + v]) * 4;
    float k0 = kb[0], k1 = kb[1], k2 = kb[2], k3 = kb[3];
    float v0 = vb[0], v1 = vb[1], v2 = vb[2], v3 = vb[3];

    float kcx = (k0 + k2) * 0.5f, kcy = (k1 + k3) * 0.5f;
    float vcx = (v0 + v2) * 0.5f, vcy = (v1 + v3) * 0.5f;
    float dx = vcx - kcx, dy = vcy - kcy;
    float dist = sqrtf(dx * dx + dy * dy + EPSF);
    float angle = atan2f(dy, dx);
    float kh = k3 - k1, vh = v3 - v1, kw = k2 - k0, vw = v2 - v0;
    float h_ov = fmaxf(fminf(k3, v3) - fmaxf(k1, v1), 0.0f);
    float h_align = h_ov / (fminf(kh, vh) + EPSF);
    float v_ov = fmaxf(fminf(k2, v2) - fmaxf(k0, v0), 0.0f);
    float v_align = v_ov / (fminf(kw, vw) + EPSF);
    float area_ratio = (vh * vw) / (kh * kw + EPSF);
    float aspect = (vw / (vh + EPSF)) / (kw / (kh + EPSF));

    float sf[8] = {dx, dy, dist, angle, h_align, v_align, area_ratio, aspect};

    float h1[64];
    #pragma unroll
    for (int j = 0; j < 64; ++j) {
        float a = sbs1[j];
        #pragma unroll
        for (int i = 0; i < 8; ++i) a += sf[i] * sWs1[i * 64 + j];
        h1[j] = fmaxf(a, 0.0f);
    }
    float h2[32];
    #pragma unroll
    for (int t = 0; t < 32; ++t) {
        float a = sbs2[t];
        #pragma unroll
        for (int j = 0; j < 64; ++j) a += h1[j] * sWs2[j * 32 + t];
        h2[t] = a;
    }
    float c0 = sc[gid];
    float score = bf2[0];
    #pragma unroll
    for (int t = 0; t < 16; ++t) {
        float f = sbf1[t] + c0 * sWf1[t];
        #pragma unroll
        for (int j = 0; j < 32; ++j) f += h2[j] * sWf1[(1 + j) * 16 + t];
        f = fmaxf(f, 0.0f);
        score += f * sWf2[t];
    }
    sc[gid] = score;
}

// ------------------------------------------------------------------
// Kernel 5: pack f32 scores + indices (as f32 values) into float d_out.
// ------------------------------------------------------------------
__global__ __launch_bounds__(256) void pack_kernel(
    const float* __restrict__ sc,      // [65536]
    const int* __restrict__ key_idx,   // [512]
    const int* __restrict__ val_idx,   // [512]
    float* __restrict__ out)           // [66560] float32
{
    const int i = blockIdx.x * 256 + threadIdx.x;
    if (i < B_ * KC * KC) {
        out[i] = sc[i];
    } else if (i < B_ * KC * KC + B_ * KC) {
        out[i] = (float)key_idx[i - B_ * KC * KC];
    } else if (i < B_ * KC * KC + 2 * B_ * KC) {
        out[i] = (float)val_idx[i - B_ * KC * KC - B_ * KC];
    }
}

// ------------------------------------------------------------------
extern "C" void kernel_launch(void* const* d_in, const int* in_sizes, int n_in,
                              void* d_out, int out_size, void* d_ws, size_t ws_size,
                              hipStream_t stream) {
    const float* seq    = (const float*)d_in[0];
    const float* logits = (const float*)d_in[1];
    const float* bboxes = (const float*)d_in[2];
    const int*   mask   = (const int*)d_in[3];
    const float* Wk   = (const float*)d_in[4];
    const float* bk   = (const float*)d_in[5];
    const float* Wv   = (const float*)d_in[6];
    const float* bv   = (const float*)d_in[7];
    const float* Wbil = (const float*)d_in[8];
    const float* bbil = (const float*)d_in[9];
    const float* Ws1  = (const float*)d_in[10];
    const float* bs1  = (const float*)d_in[11];
    const float* Ws2  = (const float*)d_in[12];
    const float* bs2  = (const float*)d_in[13];
    const float* Wf1  = (const float*)d_in[14];
    const float* bf1  = (const float*)d_in[15];
    const float* Wf2  = (const float*)d_in[16];
    const float* bf2  = (const float*)d_in[17];

    float* out = (float*)d_out;        // reference outputs are f32/int32 -> float*
    float* ws = (float*)d_ws;

    // ws layout (f32 elems): idx 1024 | krep 128K | vrep 128K | kbt 128K | scores 64K
    int*   key_idx = (int*)ws;                    // [512]
    int*   val_idx = key_idx + B_ * KC;           // [512]
    float* krep = ws + 1024;                      // [128*1024] per-batch
    float* vrep = krep + KC * H_;
    float* kbt  = vrep + KC * H_;
    float* scF  = kbt + KC * H_;                  // [B*K*V] f32

    topk_kernel<<<8, 256, 0, stream>>>(logits, mask, key_idx, val_idx);

    for (int b = 0; b < B_; ++b) {
        const float* seq_b = seq + (size_t)b * S_ * H_;
        gemm128_kernel<<<dim3(H_ / BN, KC / BM), 256, 0, stream>>>(
            seq_b, key_idx + b * KC, Wk, bk, krep);
        gemm128_kernel<<<dim3(H_ / BN, KC / BM), 256, 0, stream>>>(
            seq_b, val_idx + b * KC, Wv, bv, vrep);
        gemm128_kernel<<<dim3(H_ / BN, KC / BM), 256, 0, stream>>>(
            krep, nullptr, Wbil, nullptr, kbt);
        biaffine128_kernel<<<dim3(KC / BN, KC / BM), 256, 0, stream>>>(
            kbt, vrep, bbil, scF + (size_t)b * KC * KC);
    }

    fused_spatial_kernel<<<(B_ * KC * KC) / 256, 256, 0, stream>>>(
        bboxes, key_idx, val_idx,
        Ws1, bs1, Ws2, bs2, Wf1, bf1, Wf2, bf2, scF);

    pack_kernel<<<(B_ * KC * KC + 2 * B_ * KC + 255) / 256, 256, 0, stream>>>(
        scF, key_idx, val_idx, out);
}

// Round 5
// 364.497 us; speedup vs baseline: 3.6839x; 3.6839x over previous
//
#include <hip/hip_runtime.h>
#include <hip/hip_bf16.h>
#include <math.h>

#define B_ 4
#define S_ 2048
#define H_ 1024
#define KC 128
#define EPSF 1e-8f

// ------------------------------------------------------------------
// Kernel 1: top-K via full bitonic sort of packed u64 keys.
// key = (~mono(conf) << 32) | idx  -> ascending sort = conf desc, idx asc.
// One block per (batch, class); writes int indices to ws AND f32 copies
// directly into the d_out index regions.
// ------------------------------------------------------------------
__global__ __launch_bounds__(256) void topk_kernel(
    const float* __restrict__ logits,   // [B,S,3]
    const int*   __restrict__ mask,     // [B,S]
    int* __restrict__ key_idx,          // [B,K]
    int* __restrict__ val_idx,          // [B,K]
    float* __restrict__ out_idx)        // d_out + B*K*V
{
    __shared__ unsigned long long keys[S_];

    const int tid = threadIdx.x;
    const int blk = blockIdx.x;          // 0..7
    const int b   = blk >> 1;
    const int cls = (blk & 1) ? 2 : 1;

    for (int s = tid; s < S_; s += 256) {
        float l0 = logits[(b * S_ + s) * 3 + 0];
        float l1 = logits[(b * S_ + s) * 3 + 1];
        float l2 = logits[(b * S_ + s) * 3 + 2];
        int pred = 0; float bl = l0;
        if (l1 > bl) { bl = l1; pred = 1; }
        if (l2 > bl) { bl = l2; pred = 2; }
        float c = -1.0f;                 // sentinel below any valid conf (>=1/3)
        if (pred == cls && mask[b * S_ + s] == 1) {
            double m = (double)bl;
            double e0 = exp((double)l0 - m);
            double e1 = exp((double)l1 - m);
            double e2 = exp((double)l2 - m);
            c = (float)(((cls == 1) ? e1 : e2) / (e0 + e1 + e2));
        }
        unsigned int u = __float_as_uint(c);
        unsigned int mono = (u & 0x80000000u) ? ~u : (u | 0x80000000u);
        keys[s] = ((unsigned long long)(~mono) << 32) | (unsigned int)s;
    }
    __syncthreads();

    for (int k = 2; k <= S_; k <<= 1) {
        for (int j = k >> 1; j > 0; j >>= 1) {
            for (int t = tid; t < S_ / 2; t += 256) {
                int i = ((t & ~(j - 1)) << 1) | (t & (j - 1));
                int p = i | j;
                bool up = ((i & k) == 0);
                unsigned long long a = keys[i], c2 = keys[p];
                if (up ? (a > c2) : (a < c2)) { keys[i] = c2; keys[p] = a; }
            }
            __syncthreads();
        }
    }

    int* idx_out = (blk & 1) ? (val_idx + b * KC) : (key_idx + b * KC);
    float* oidx  = out_idx + ((blk & 1) ? B_ * KC : 0) + b * KC;
    for (int it = tid; it < KC; it += 256) {
        int sel = (int)(keys[it] & 0xffffffffu);
        idx_out[it] = sel;
        oidx[it] = (float)sel;
    }
}

// ------------------------------------------------------------------
// Kernel 2: batched C[512,H] = gather(A)[512,H] @ W[H,H] (+bias), f32.
// 64x64 tile, BK=16, 256 threads, 4x4 per thread.
// ------------------------------------------------------------------
#define BM 64
#define BN 64
#define BKc 16

__global__ __launch_bounds__(256) void gemm_kernel(
    const float* __restrict__ Abase, // seq [B,S,H] (idx!=null) or [512,H]
    const int*   __restrict__ idx,   // [512] concat over batches, or nullptr
    const float* __restrict__ W,     // [H,H] row-major
    const float* __restrict__ bias,  // [H] or nullptr
    float* __restrict__ Cout)        // [512,H]
{
    __shared__ float As[BM][BKc + 1];
    __shared__ float Bs[BKc][BN];
    const int tid = threadIdx.x;
    const int m0 = blockIdx.y * BM;
    const int n0 = blockIdx.x * BN;
    const int ty = tid >> 4, tx = tid & 15;
    float acc[4][4] = {};

    const int ar = tid >> 2, aq = (tid & 3) * 4;   // A tile: 64 x 16
    const int am = m0 + ar;
    const float* arow = idx
        ? (Abase + ((size_t)(am >> 7) * S_ + idx[am]) * H_)
        : (Abase + (size_t)am * H_);
    const int br = tid >> 4, bq = (tid & 15) * 4;  // B tile: 16 x 64

    for (int h0 = 0; h0 < H_; h0 += BKc) {
        float4 av = *(const float4*)(arow + h0 + aq);
        As[ar][aq + 0] = av.x; As[ar][aq + 1] = av.y;
        As[ar][aq + 2] = av.z; As[ar][aq + 3] = av.w;
        float4 bv = *(const float4*)(W + (size_t)(h0 + br) * H_ + n0 + bq);
        *(float4*)&Bs[br][bq] = bv;
        __syncthreads();
        #pragma unroll
        for (int kk = 0; kk < BKc; ++kk) {
            float a_[4], b_[4];
            #pragma unroll
            for (int i = 0; i < 4; ++i) a_[i] = As[ty * 4 + i][kk];
            #pragma unroll
            for (int j = 0; j < 4; ++j) b_[j] = Bs[kk][tx * 4 + j];
            #pragma unroll
            for (int i = 0; i < 4; ++i)
                #pragma unroll
                for (int j = 0; j < 4; ++j) acc[i][j] += a_[i] * b_[j];
        }
        __syncthreads();
    }
    #pragma unroll
    for (int i = 0; i < 4; ++i) {
        int m = m0 + ty * 4 + i;
        #pragma unroll
        for (int j = 0; j < 4; ++j) {
            int n = n0 + tx * 4 + j;
            Cout[(size_t)m * H_ + n] = acc[i][j] + (bias ? bias[n] : 0.0f);
        }
    }
}

// ------------------------------------------------------------------
// Kernel 3: biaffine, batched over z. scores[b,k,v] -> f32 d_out directly.
// ------------------------------------------------------------------
__global__ __launch_bounds__(256) void biaffine_kernel(
    const float* __restrict__ kbt,   // [512,H] (b-major)
    const float* __restrict__ vrep,  // [512,H]
    const float* __restrict__ bbil,  // scalar
    float* __restrict__ scores)      // [B,K,V] = d_out
{
    __shared__ float As[BM][BKc + 1];
    __shared__ float Bs[BM][BKc + 1];
    const int tid = threadIdx.x;
    const int b  = blockIdx.z;
    const int m0 = blockIdx.y * BM;
    const int n0 = blockIdx.x * BN;
    const int ty = tid >> 4, tx = tid & 15;
    float acc[4][4] = {};

    const int ar = tid >> 2, aq = (tid & 3) * 4;
    const float* arow = kbt  + ((size_t)b * KC + m0 + ar) * H_;
    const float* brow = vrep + ((size_t)b * KC + n0 + ar) * H_;

    for (int h0 = 0; h0 < H_; h0 += BKc) {
        float4 av = *(const float4*)(arow + h0 + aq);
        As[ar][aq + 0] = av.x; As[ar][aq + 1] = av.y;
        As[ar][aq + 2] = av.z; As[ar][aq + 3] = av.w;
        float4 bv = *(const float4*)(brow + h0 + aq);
        Bs[ar][aq + 0] = bv.x; Bs[ar][aq + 1] = bv.y;
        Bs[ar][aq + 2] = bv.z; Bs[ar][aq + 3] = bv.w;
        __syncthreads();
        #pragma unroll
        for (int kk = 0; kk < BKc; ++kk) {
            float a_[4], b_[4];
            #pragma unroll
            for (int i = 0; i < 4; ++i) a_[i] = As[ty * 4 + i][kk];
            #pragma unroll
            for (int j = 0; j < 4; ++j) b_[j] = Bs[tx * 4 + j][kk];
            #pragma unroll
            for (int i = 0; i < 4; ++i)
                #pragma unroll
                for (int j = 0; j < 4; ++j) acc[i][j] += a_[i] * b_[j];
        }
        __syncthreads();
    }
    float bb = *bbil;
    #pragma unroll
    for (int i = 0; i < 4; ++i) {
        int m = m0 + ty * 4 + i;
        #pragma unroll
        for (int j = 0; j < 4; ++j) {
            int n = n0 + tx * 4 + j;
            scores[((size_t)b * KC + m) * KC + n] = acc[i][j] + bb;
        }
    }
}

// ------------------------------------------------------------------
// Kernel 4: spatial features + MLP(8->64->32) + final MLP(33->16->1).
// Reads f32 biaffine from d_out, overwrites with final score in place.
// ------------------------------------------------------------------
__global__ __launch_bounds__(256) void fused_spatial_kernel(
    const float* __restrict__ bboxes,  // [B,S,4]
    const int* __restrict__ key_idx, const int* __restrict__ val_idx,
    const float* __restrict__ Ws1, const float* __restrict__ bs1,
    const float* __restrict__ Ws2, const float* __restrict__ bs2,
    const float* __restrict__ Wf1, const float* __restrict__ bf1,
    const float* __restrict__ Wf2, const float* __restrict__ bf2,
    float* sc)                          // [B,K,V] (biaffine in, score out)
{
    __shared__ float sWs1[8 * 64];
    __shared__ float sbs1[64];
    __shared__ float sWs2[64 * 32];
    __shared__ float sbs2[32];
    __shared__ float sWf1[33 * 16];
    __shared__ float sbf1[16];
    __shared__ float sWf2[16];

    const int tid = threadIdx.x;
    for (int i = tid; i < 8 * 64;  i += 256) sWs1[i] = Ws1[i];
    for (int i = tid; i < 64;      i += 256) sbs1[i] = bs1[i];
    for (int i = tid; i < 64 * 32; i += 256) sWs2[i] = Ws2[i];
    for (int i = tid; i < 32;      i += 256) sbs2[i] = bs2[i];
    for (int i = tid; i < 33 * 16; i += 256) sWf1[i] = Wf1[i];
    for (int i = tid; i < 16;      i += 256) sbf1[i] = bf1[i];
    for (int i = tid; i < 16;      i += 256) sWf2[i] = Wf2[i];
    __syncthreads();

    const int gid = blockIdx.x * 256 + tid;   // < B*K*V = 65536
    const int b = gid >> 14;
    const int rem = gid & 16383;
    const int k = rem >> 7;
    const int v = rem & 127;

    const float* kb = bboxes + ((size_t)b * S_ + key_idx[b * KC + k]) * 4;
    const float* vb = bboxes + ((size_t)b * S_ + val_idx[b * KC + v]) * 4;
    float k0 = kb[0], k1 = kb[1], k2 = kb[2], k3 = kb[3];
    float v0 = vb[0], v1 = vb[1], v2 = vb[2], v3 = vb[3];

    float kcx = (k0 + k2) * 0.5f, kcy = (k1 + k3) * 0.5f;
    float vcx = (v0 + v2) * 0.5f, vcy = (v1 + v3) * 0.5f;
    float dx = vcx - kcx, dy = vcy - kcy;
    float dist = sqrtf(dx * dx + dy * dy + EPSF);
    float angle = atan2f(dy, dx);
    float kh = k3 - k1, vh = v3 - v1, kw = k2 - k0, vw = v2 - v0;
    float h_ov = fmaxf(fminf(k3, v3) - fmaxf(k1, v1), 0.0f);
    float h_align = h_ov / (fminf(kh, vh) + EPSF);
    float v_ov = fmaxf(fminf(k2, v2) - fmaxf(k0, v0), 0.0f);
    float v_align = v_ov / (fminf(kw, vw) + EPSF);
    float area_ratio = (vh * vw) / (kh * kw + EPSF);
    float aspect = (vw / (vh + EPSF)) / (kw / (kh + EPSF));

    float sf[8] = {dx, dy, dist, angle, h_align, v_align, area_ratio, aspect};

    float h1[64];
    #pragma unroll
    for (int j = 0; j < 64; ++j) {
        float a = sbs1[j];
        #pragma unroll
        for (int i = 0; i < 8; ++i) a += sf[i] * sWs1[i * 64 + j];
        h1[j] = fmaxf(a, 0.0f);
    }
    float h2[32];
    #pragma unroll
    for (int t = 0; t < 32; ++t) {
        float a = sbs2[t];
        #pragma unroll
        for (int j = 0; j < 64; ++j) a += h1[j] * sWs2[j * 32 + t];
        h2[t] = a;
    }
    float c0 = sc[gid];
    float score = bf2[0];
    #pragma unroll
    for (int t = 0; t < 16; ++t) {
        float f = sbf1[t] + c0 * sWf1[t];
        #pragma unroll
        for (int j = 0; j < 32; ++j) f += h2[j] * sWf1[(1 + j) * 16 + t];
        f = fmaxf(f, 0.0f);
        score += f * sWf2[t];
    }
    sc[gid] = score;
}

// ------------------------------------------------------------------
extern "C" void kernel_launch(void* const* d_in, const int* in_sizes, int n_in,
                              void* d_out, int out_size, void* d_ws, size_t ws_size,
                              hipStream_t stream) {
    const float* seq    = (const float*)d_in[0];
    const float* logits = (const float*)d_in[1];
    const float* bboxes = (const float*)d_in[2];
    const int*   mask   = (const int*)d_in[3];
    const float* Wk   = (const float*)d_in[4];
    const float* bk   = (const float*)d_in[5];
    const float* Wv   = (const float*)d_in[6];
    const float* bv   = (const float*)d_in[7];
    const float* Wbil = (const float*)d_in[8];
    const float* bbil = (const float*)d_in[9];
    const float* Ws1  = (const float*)d_in[10];
    const float* bs1  = (const float*)d_in[11];
    const float* Ws2  = (const float*)d_in[12];
    const float* bs2  = (const float*)d_in[13];
    const float* Wf1  = (const float*)d_in[14];
    const float* bf1  = (const float*)d_in[15];
    const float* Wf2  = (const float*)d_in[16];
    const float* bf2  = (const float*)d_in[17];

    float* out = (float*)d_out;        // scores [65536] | key_idx | val_idx (f32)
    float* ws = (float*)d_ws;

    // ws: idx 1024 f32 (4KB) | bufA 512*1024 (2MB) | bufB 512*1024 (2MB)
    int*   key_idx = (int*)ws;                    // [512]
    int*   val_idx = key_idx + B_ * KC;           // [512]
    float* bufA = ws + 1024;                      // krep, then vrep
    float* bufB = bufA + B_ * KC * H_;            // kbt

    topk_kernel<<<8, 256, 0, stream>>>(logits, mask, key_idx, val_idx,
                                       out + B_ * KC * KC);

    // krep = gather(seq, key_idx) @ Wk + bk       [512,1024]
    gemm_kernel<<<dim3(H_ / BN, (B_ * KC) / BM), 256, 0, stream>>>(
        seq, key_idx, Wk, bk, bufA);
    // kbt = krep @ Wbil                           [512,1024]
    gemm_kernel<<<dim3(H_ / BN, (B_ * KC) / BM), 256, 0, stream>>>(
        bufA, nullptr, Wbil, nullptr, bufB);
    // vrep = gather(seq, val_idx) @ Wv + bv       [512,1024]  (reuse bufA)
    gemm_kernel<<<dim3(H_ / BN, (B_ * KC) / BM), 256, 0, stream>>>(
        seq, val_idx, Wv, bv, bufA);
    // scores = kbt . vrep^T + bbil -> d_out
    biaffine_kernel<<<dim3(KC / BN, KC / BM, B_), 256, 0, stream>>>(
        bufB, bufA, bbil, out);
    // in-place: scores = final MLP(biaffine, spatial)
    fused_spatial_kernel<<<(B_ * KC * KC) / 256, 256, 0, stream>>>(
        bboxes, key_idx, val_idx,
        Ws1, bs1, Ws2, bs2, Wf1, bf1, Wf2, bf2, out);
}

// Round 6
// 128.724 us; speedup vs baseline: 10.4315x; 2.8316x over previous
//
#include <hip/hip_runtime.h>
#include <hip/hip_bf16.h>
#include <math.h>

#define B_ 4
#define S_ 2048
#define H_ 1024
#define KC 128
#define EPSF 1e-8f

typedef __attribute__((ext_vector_type(8))) short bf16x8;
typedef __attribute__((ext_vector_type(4))) float f32x4;

static __device__ inline unsigned short f2b(float f) {
    unsigned u = __float_as_uint(f);
    return (unsigned short)((u + 0x7fffu + ((u >> 16) & 1u)) >> 16);  // RNE
}

// ------------------------------------------------------------------
// Kernel 1: top-K via bitonic sort of packed u64 keys.
// ------------------------------------------------------------------
__global__ __launch_bounds__(256) void topk_kernel(
    const float* __restrict__ logits,   // [B,S,3]
    const int*   __restrict__ mask,     // [B,S]
    int* __restrict__ key_idx,          // [B,K]
    int* __restrict__ val_idx,          // [B,K]
    float* __restrict__ out_idx)        // d_out + B*K*V
{
    __shared__ unsigned long long keys[S_];

    const int tid = threadIdx.x;
    const int blk = blockIdx.x;          // 0..7
    const int b   = blk >> 1;
    const int cls = (blk & 1) ? 2 : 1;

    for (int s = tid; s < S_; s += 256) {
        float l0 = logits[(b * S_ + s) * 3 + 0];
        float l1 = logits[(b * S_ + s) * 3 + 1];
        float l2 = logits[(b * S_ + s) * 3 + 2];
        int pred = 0; float bl = l0;
        if (l1 > bl) { bl = l1; pred = 1; }
        if (l2 > bl) { bl = l2; pred = 2; }
        float c = -1.0f;
        if (pred == cls && mask[b * S_ + s] == 1) {
            double m = (double)bl;
            double e0 = exp((double)l0 - m);
            double e1 = exp((double)l1 - m);
            double e2 = exp((double)l2 - m);
            c = (float)(((cls == 1) ? e1 : e2) / (e0 + e1 + e2));
        }
        unsigned int u = __float_as_uint(c);
        unsigned int mono = (u & 0x80000000u) ? ~u : (u | 0x80000000u);
        keys[s] = ((unsigned long long)(~mono) << 32) | (unsigned int)s;
    }
    __syncthreads();

    for (int k = 2; k <= S_; k <<= 1) {
        for (int j = k >> 1; j > 0; j >>= 1) {
            for (int t = tid; t < S_ / 2; t += 256) {
                int i = ((t & ~(j - 1)) << 1) | (t & (j - 1));
                int p = i | j;
                bool up = ((i & k) == 0);
                unsigned long long a = keys[i], c2 = keys[p];
                if (up ? (a > c2) : (a < c2)) { keys[i] = c2; keys[p] = a; }
            }
            __syncthreads();
        }
    }

    int* idx_out = (blk & 1) ? (val_idx + b * KC) : (key_idx + b * KC);
    float* oidx  = out_idx + ((blk & 1) ? B_ * KC : 0) + b * KC;
    for (int it = tid; it < KC; it += 256) {
        int sel = (int)(keys[it] & 0xffffffffu);
        idx_out[it] = sel;
        oidx[it] = (float)sel;
    }
}

// ------------------------------------------------------------------
// Kernel 2: W [K][N] f32 -> Wt [N][K] bf16 (transpose+convert), z=weight.
// ------------------------------------------------------------------
__global__ __launch_bounds__(256) void convw_kernel(
    const float* __restrict__ Wk, const float* __restrict__ Wv,
    const float* __restrict__ Wbil,
    unsigned short* __restrict__ Wt)   // [3][1024][1024]
{
    __shared__ float tile[32][33];
    const int z = blockIdx.z;
    const float* Win = (z == 0) ? Wk : (z == 1) ? Wv : Wbil;
    unsigned short* out = Wt + (size_t)z * H_ * H_;
    const int n0 = blockIdx.x * 32, k0 = blockIdx.y * 32;
    const int tid = threadIdx.x;
    const int r = tid >> 3, c0 = (tid & 7) * 4;

    const float* src = Win + (size_t)(k0 + r) * H_ + n0 + c0;
    float4 v = *(const float4*)src;
    tile[r][c0 + 0] = v.x; tile[r][c0 + 1] = v.y;
    tile[r][c0 + 2] = v.z; tile[r][c0 + 3] = v.w;
    __syncthreads();

    short4 o;
    o.x = (short)f2b(tile[c0 + 0][r]);
    o.y = (short)f2b(tile[c0 + 1][r]);
    o.z = (short)f2b(tile[c0 + 2][r]);
    o.w = (short)f2b(tile[c0 + 3][r]);
    *(short4*)(out + (size_t)(n0 + r) * H_ + k0 + c0) = o;
}

// ------------------------------------------------------------------
// Kernel 3: gather seq rows by idx, convert to bf16. rows 0..511 keys,
// 512..1023 vals.  Abf [1024][1024] bf16.
// ------------------------------------------------------------------
__global__ __launch_bounds__(256) void gatherconv_kernel(
    const float* __restrict__ seq,     // [B,S,H]
    const int* __restrict__ key_idx, const int* __restrict__ val_idx,
    unsigned short* __restrict__ Abf)  // [1024][1024]
{
    const int row = blockIdx.x;
    const int tid = threadIdx.x;
    int b, srow;
    if (row < 512) { b = row >> 7; srow = key_idx[row]; }
    else           { b = (row - 512) >> 7; srow = val_idx[row - 512]; }
    const float* src = seq + ((size_t)b * S_ + srow) * H_ + tid * 4;
    float4 v = *(const float4*)src;
    short4 o;
    o.x = (short)f2b(v.x); o.y = (short)f2b(v.y);
    o.z = (short)f2b(v.z); o.w = (short)f2b(v.w);
    *(short4*)(Abf + (size_t)row * H_ + tid * 4) = o;
}

// ------------------------------------------------------------------
// Kernel 4: MFMA GEMM  C[m][n] = A[m][:] . Wt[n][:]  (+bias), bf16 in,
// bf16 out. 1 wave per 32x64 tile, no LDS. z selects {A-slice, Wt, bias}.
// ------------------------------------------------------------------
__global__ __launch_bounds__(64) void gemm_mfma_kernel(
    const unsigned short* __restrict__ A,   // [z*512+512][1024] bf16
    const unsigned short* __restrict__ Wt,  // [z][1024][1024] bf16 (N-major)
    const float* __restrict__ b0, const float* __restrict__ b1,
    unsigned short* __restrict__ Cout)      // [z*512+512][1024] bf16
{
    const int z = blockIdx.z;
    A    += (size_t)z * 512 * H_;
    Wt   += (size_t)z * H_ * H_;
    Cout += (size_t)z * 512 * H_;
    const float* bias = z ? b1 : b0;

    const int l  = threadIdx.x;
    const int m0 = blockIdx.y * 32;
    const int n0 = blockIdx.x * 64;
    const int r  = l & 15;
    const int kb = (l >> 4) * 8;

    f32x4 acc[2][4] = {};
    const unsigned short* a0 = A + (size_t)(m0 + r) * H_ + kb;
    const unsigned short* a1 = a0 + 16 * H_;
    const unsigned short* w0 = Wt + (size_t)(n0 + r) * H_ + kb;

    #pragma unroll 2
    for (int k0 = 0; k0 < H_; k0 += 32) {
        bf16x8 av[2], bv[4];
        av[0] = *(const bf16x8*)(a0 + k0);
        av[1] = *(const bf16x8*)(a1 + k0);
        #pragma unroll
        for (int j = 0; j < 4; ++j)
            bv[j] = *(const bf16x8*)(w0 + (size_t)j * 16 * H_ + k0);
        #pragma unroll
        for (int i = 0; i < 2; ++i)
            #pragma unroll
            for (int j = 0; j < 4; ++j)
                acc[i][j] = __builtin_amdgcn_mfma_f32_16x16x32_bf16(
                    av[i], bv[j], acc[i][j], 0, 0, 0);
    }

    const int orow = (l >> 4) * 4, ocol = l & 15;
    #pragma unroll
    for (int i = 0; i < 2; ++i) {
        #pragma unroll
        for (int j = 0; j < 4; ++j) {
            int n = n0 + j * 16 + ocol;
            float bv_ = bias ? bias[n] : 0.0f;
            #pragma unroll
            for (int g = 0; g < 4; ++g) {
                int m = m0 + i * 16 + orow + g;
                Cout[(size_t)m * H_ + n] = f2b(acc[i][j][g] + bv_);
            }
        }
    }
}

// ------------------------------------------------------------------
// Kernel 5: biaffine via MFMA: scores[b,k,v] = kbt[bk,:] . vrep[bv,:] + bbil
// ------------------------------------------------------------------
__global__ __launch_bounds__(64) void biaffine_mfma_kernel(
    const unsigned short* __restrict__ kbt,   // [512][1024] bf16 (b-major)
    const unsigned short* __restrict__ vrep,  // [512][1024] bf16
    const float* __restrict__ bbil,
    float* __restrict__ scores)               // [B,K,V] = d_out
{
    const int b  = blockIdx.z;
    const int l  = threadIdx.x;
    const int m0 = blockIdx.y * 32;
    const int n0 = blockIdx.x * 64;
    const int r  = l & 15;
    const int kb = (l >> 4) * 8;

    f32x4 acc[2][4] = {};
    const unsigned short* a0 = kbt  + (size_t)(b * KC + m0 + r) * H_ + kb;
    const unsigned short* a1 = a0 + 16 * H_;
    const unsigned short* w0 = vrep + (size_t)(b * KC + n0 + r) * H_ + kb;

    #pragma unroll 2
    for (int k0 = 0; k0 < H_; k0 += 32) {
        bf16x8 av[2], bv[4];
        av[0] = *(const bf16x8*)(a0 + k0);
        av[1] = *(const bf16x8*)(a1 + k0);
        #pragma unroll
        for (int j = 0; j < 4; ++j)
            bv[j] = *(const bf16x8*)(w0 + (size_t)j * 16 * H_ + k0);
        #pragma unroll
        for (int i = 0; i < 2; ++i)
            #pragma unroll
            for (int j = 0; j < 4; ++j)
                acc[i][j] = __builtin_amdgcn_mfma_f32_16x16x32_bf16(
                    av[i], bv[j], acc[i][j], 0, 0, 0);
    }

    float bb = *bbil;
    const int orow = (l >> 4) * 4, ocol = l & 15;
    #pragma unroll
    for (int i = 0; i < 2; ++i)
        #pragma unroll
        for (int j = 0; j < 4; ++j)
            #pragma unroll
            for (int g = 0; g < 4; ++g) {
                int m = m0 + i * 16 + orow + g;
                int n = n0 + j * 16 + ocol;
                scores[((size_t)b * KC + m) * KC + n] = acc[i][j][g] + bb;
            }
}

// ------------------------------------------------------------------
// Kernel 6: spatial features + MLP(8->64->32) + final MLP(33->16->1).
// Register-light: incremental h1_j -> h2 accumulation. In-place on d_out.
// ------------------------------------------------------------------
__global__ __launch_bounds__(128) void fused_spatial_kernel(
    const float* __restrict__ bboxes,  // [B,S,4]
    const int* __restrict__ key_idx, const int* __restrict__ val_idx,
    const float* __restrict__ Ws1, const float* __restrict__ bs1,
    const float* __restrict__ Ws2, const float* __restrict__ bs2,
    const float* __restrict__ Wf1, const float* __restrict__ bf1,
    const float* __restrict__ Wf2, const float* __restrict__ bf2,
    float* sc)                          // [B,K,V] (biaffine in, score out)
{
    __shared__ float sWs1T[64 * 8];    // [j][i] = Ws1[i*64+j]
    __shared__ float sbs1[64];
    __shared__ float sWs2[64 * 32];    // [j][t] (row-contiguous, as input)
    __shared__ float sbs2[32];
    __shared__ float sWf1T[16 * 33];   // [t][r] = Wf1[r*16+t]
    __shared__ float sbf1[16];
    __shared__ float sWf2[16];

    const int tid = threadIdx.x;
    for (int i = tid; i < 512; i += 128) sWs1T[i] = Ws1[(i & 7) * 64 + (i >> 3)];
    for (int i = tid; i < 64;  i += 128) sbs1[i] = bs1[i];
    for (int i = tid; i < 2048; i += 128) sWs2[i] = Ws2[i];
    for (int i = tid; i < 32;  i += 128) sbs2[i] = bs2[i];
    for (int i = tid; i < 528; i += 128) { int t = i / 33, r = i % 33; sWf1T[i] = Wf1[r * 16 + t]; }
    for (int i = tid; i < 16;  i += 128) sbf1[i] = bf1[i];
    for (int i = tid; i < 16;  i += 128) sWf2[i] = Wf2[i];
    __syncthreads();

    const int gid = blockIdx.x * 128 + tid;   // < 65536
    const int b = gid >> 14;
    const int rem = gid & 16383;
    const int k = rem >> 7;
    const int v = rem & 127;

    const float* kbx = bboxes + ((size_t)b * S_ + key_idx[b * KC + k]) * 4;
    const float* vbx = bboxes + ((size_t)b * S_ + val_idx[b * KC + v]) * 4;
    float k0 = kbx[0], k1 = kbx[1], k2 = kbx[2], k3 = kbx[3];
    float v0 = vbx[0], v1 = vbx[1], v2 = vbx[2], v3 = vbx[3];

    float kcx = (k0 + k2) * 0.5f, kcy = (k1 + k3) * 0.5f;
    float vcx = (v0 + v2) * 0.5f, vcy = (v1 + v3) * 0.5f;
    float dx = vcx - kcx, dy = vcy - kcy;
    float dist = sqrtf(dx * dx + dy * dy + EPSF);
    float angle = atan2f(dy, dx);
    float kh = k3 - k1, vh = v3 - v1, kw = k2 - k0, vw = v2 - v0;
    float h_ov = fmaxf(fminf(k3, v3) - fmaxf(k1, v1), 0.0f);
    float h_align = h_ov / (fminf(kh, vh) + EPSF);
    float v_ov = fmaxf(fminf(k2, v2) - fmaxf(k0, v0), 0.0f);
    float v_align = v_ov / (fminf(kw, vw) + EPSF);
    float area_ratio = (vh * vw) / (kh * kw + EPSF);
    float aspect = (vw / (vh + EPSF)) / (kw / (kh + EPSF));

    float sf[8] = {dx, dy, dist, angle, h_align, v_align, area_ratio, aspect};

    float h2[32];
    #pragma unroll
    for (int t = 0; t < 32; ++t) h2[t] = sbs2[t];

    for (int j = 0; j < 64; ++j) {
        const float* w1 = &sWs1T[j * 8];
        float a = sbs1[j];
        #pragma unroll
        for (int i = 0; i < 8; ++i) a += sf[i] * w1[i];
        a = fmaxf(a, 0.0f);
        const float* w2 = &sWs2[j * 32];
        #pragma unroll
        for (int t = 0; t < 32; ++t) h2[t] += a * w2[t];
    }

    float c0 = sc[gid];
    float score = bf2[0];
    for (int t = 0; t < 16; ++t) {
        const float* w = &sWf1T[t * 33];
        float f = sbf1[t] + c0 * w[0];
        #pragma unroll
        for (int j = 0; j < 32; ++j) f += h2[j] * w[1 + j];
        score += fmaxf(f, 0.0f) * sWf2[t];
    }
    sc[gid] = score;
}

// ------------------------------------------------------------------
extern "C" void kernel_launch(void* const* d_in, const int* in_sizes, int n_in,
                              void* d_out, int out_size, void* d_ws, size_t ws_size,
                              hipStream_t stream) {
    const float* seq    = (const float*)d_in[0];
    const float* logits = (const float*)d_in[1];
    const float* bboxes = (const float*)d_in[2];
    const int*   mask   = (const int*)d_in[3];
    const float* Wk   = (const float*)d_in[4];
    const float* bk   = (const float*)d_in[5];
    const float* Wv   = (const float*)d_in[6];
    const float* bv   = (const float*)d_in[7];
    const float* Wbil = (const float*)d_in[8];
    const float* bbil = (const float*)d_in[9];
    const float* Ws1  = (const float*)d_in[10];
    const float* bs1  = (const float*)d_in[11];
    const float* Ws2  = (const float*)d_in[12];
    const float* bs2  = (const float*)d_in[13];
    const float* Wf1  = (const float*)d_in[14];
    const float* bf1  = (const float*)d_in[15];
    const float* Wf2  = (const float*)d_in[16];
    const float* bf2  = (const float*)d_in[17];

    float* out = (float*)d_out;        // scores [65536] | key_idx | val_idx
    char* ws = (char*)d_ws;

    // ws layout:
    //   idx:  1024 int  (4 KB)
    //   Wt:   3 * 1024*1024 bf16  (6 MB)   [WtK | WtV | WtBil]
    //   Abf:  1024*1024 bf16 (2 MB)  -- later reused as kbt [512*1024] bf16
    //   reps: 2 * 512*1024 bf16 (2 MB)     [krep | vrep]
    int* key_idx = (int*)ws;
    int* val_idx = key_idx + B_ * KC;
    unsigned short* Wt   = (unsigned short*)(ws + 4096);
    unsigned short* Abf  = Wt + (size_t)3 * H_ * H_;
    unsigned short* kbt  = Abf;                       // alias (Abf dead by then)
    unsigned short* reps = Abf + (size_t)H_ * H_;
    unsigned short* krep = reps;
    unsigned short* vrep = reps + (size_t)512 * H_;

    convw_kernel<<<dim3(32, 32, 3), 256, 0, stream>>>(Wk, Wv, Wbil, Wt);
    topk_kernel<<<8, 256, 0, stream>>>(logits, mask, key_idx, val_idx,
                                       out + B_ * KC * KC);
    gatherconv_kernel<<<1024, 256, 0, stream>>>(seq, key_idx, val_idx, Abf);

    // z=0: krep = keys @ WtK + bk ; z=1: vrep = vals @ WtV + bv
    gemm_mfma_kernel<<<dim3(16, 16, 2), 64, 0, stream>>>(
        Abf, Wt, bk, bv, reps);
    // kbt = krep @ WtBil (no bias)
    gemm_mfma_kernel<<<dim3(16, 16, 1), 64, 0, stream>>>(
        krep, Wt + (size_t)2 * H_ * H_, nullptr, nullptr, kbt);

    biaffine_mfma_kernel<<<dim3(2, 4, B_), 64, 0, stream>>>(
        kbt, vrep, bbil, out);

    fused_spatial_kernel<<<(B_ * KC * KC) / 128, 128, 0, stream>>>(
        bboxes, key_idx, val_idx,
        Ws1, bs1, Ws2, bs2, Wf1, bf1, Wf2, bf2, out);
}

// Round 7
// 100.512 us; speedup vs baseline: 13.3595x; 1.2807x over previous
//
#include <hip/hip_runtime.h>
#include <hip/hip_bf16.h>
#include <math.h>

#define B_ 4
#define S_ 2048
#define H_ 1024
#define KC 128
#define EPSF 1e-8f

typedef __attribute__((ext_vector_type(8))) short bf16x8;
typedef __attribute__((ext_vector_type(4))) float f32x4;

static __device__ inline unsigned short f2b(float f) {
    unsigned u = __float_as_uint(f);
    return (unsigned short)((u + 0x7fffu + ((u >> 16) & 1u)) >> 16);  // RNE
}

static __device__ inline unsigned long long shflx64(unsigned long long v, int m) {
    int lo = __shfl_xor((int)(unsigned)(v & 0xffffffffull), m, 64);
    int hi = __shfl_xor((int)(unsigned)(v >> 32), m, 64);
    return ((unsigned long long)(unsigned)hi << 32) | (unsigned)lo;
}

// Cross-lane bitonic stage (j>=8): partner lane = lane ^ (j>>3), same reg.
#define CROSS_STAGE(k, j) do {                                              \
    const int lm = (j) >> 3;                                                \
    const bool upL  = (((lane) * 8) & (k)) == 0;                            \
    const bool lowr = ((lane) & lm) == 0;                                   \
    _Pragma("unroll")                                                       \
    for (int r = 0; r < 8; ++r) {                                           \
        unsigned long long o = shflx64(e[r], lm);                           \
        e[r] = ((upL == lowr) == (e[r] < o)) ? e[r] : o;                    \
    }                                                                       \
} while (0)

// Intra-lane bitonic stage (j in {1,2,4}): static register compare-swap.
#define INTRA_STAGE(j, k) do {                                              \
    _Pragma("unroll")                                                       \
    for (int r = 0; r < 8; ++r) if (!(r & (j))) {                           \
        bool up = ((((lane) * 8 + r) & (k)) == 0);                          \
        unsigned long long a = e[r], b = e[r | (j)];                        \
        if (up ? (a > b) : (a < b)) { e[r] = b; e[r | (j)] = a; }           \
    }                                                                       \
} while (0)

// Full ascending bitonic sort of 512 u64: lane l holds elements l*8..l*8+7.
static __device__ inline void wave_sort512(unsigned long long e[8], int lane) {
    INTRA_STAGE(1, 2);
    INTRA_STAGE(2, 4);  INTRA_STAGE(1, 4);
    INTRA_STAGE(4, 8);  INTRA_STAGE(2, 8);  INTRA_STAGE(1, 8);
    CROSS_STAGE(16, 8);
    INTRA_STAGE(4, 16); INTRA_STAGE(2, 16); INTRA_STAGE(1, 16);
    CROSS_STAGE(32, 16); CROSS_STAGE(32, 8);
    INTRA_STAGE(4, 32); INTRA_STAGE(2, 32); INTRA_STAGE(1, 32);
    CROSS_STAGE(64, 32); CROSS_STAGE(64, 16); CROSS_STAGE(64, 8);
    INTRA_STAGE(4, 64); INTRA_STAGE(2, 64); INTRA_STAGE(1, 64);
    CROSS_STAGE(128, 64); CROSS_STAGE(128, 32); CROSS_STAGE(128, 16);
    CROSS_STAGE(128, 8);
    INTRA_STAGE(4, 128); INTRA_STAGE(2, 128); INTRA_STAGE(1, 128);
    CROSS_STAGE(256, 128); CROSS_STAGE(256, 64); CROSS_STAGE(256, 32);
    CROSS_STAGE(256, 16); CROSS_STAGE(256, 8);
    INTRA_STAGE(4, 256); INTRA_STAGE(2, 256); INTRA_STAGE(1, 256);
    CROSS_STAGE(512, 256); CROSS_STAGE(512, 128); CROSS_STAGE(512, 64);
    CROSS_STAGE(512, 32); CROSS_STAGE(512, 16); CROSS_STAGE(512, 8);
    INTRA_STAGE(4, 512); INTRA_STAGE(2, 512); INTRA_STAGE(1, 512);
}

// ------------------------------------------------------------------
// Kernel 1 (prep): blocks 0..3071 transpose+convert weights to bf16;
// blocks 3072..3079 do top-K selection (register bitonic, 1 barrier).
// ------------------------------------------------------------------
__global__ __launch_bounds__(256) void prep_kernel(
    const float* __restrict__ Wk, const float* __restrict__ Wv,
    const float* __restrict__ Wbil,
    unsigned short* __restrict__ Wt,    // [3][1024][1024] bf16 (N-major)
    const float* __restrict__ logits,   // [B,S,3]
    const int*   __restrict__ mask,     // [B,S]
    int* __restrict__ key_idx,          // [B,K]
    int* __restrict__ val_idx,          // [B,K]
    float* __restrict__ out_idx)        // d_out + B*K*V
{
    __shared__ float tile[32][33];
    __shared__ unsigned long long cand[512];
    const int tid = threadIdx.x;

    if (blockIdx.x < 3072) {
        // ---- weight transpose+convert ----
        const int z = blockIdx.x >> 10;
        const int remb = blockIdx.x & 1023;
        const float* Win = (z == 0) ? Wk : (z == 1) ? Wv : Wbil;
        unsigned short* out = Wt + (size_t)z * H_ * H_;
        const int n0 = (remb & 31) * 32, k0 = (remb >> 5) * 32;
        const int r = tid >> 3, c0 = (tid & 7) * 4;

        float4 v = *(const float4*)(Win + (size_t)(k0 + r) * H_ + n0 + c0);
        tile[r][c0 + 0] = v.x; tile[r][c0 + 1] = v.y;
        tile[r][c0 + 2] = v.z; tile[r][c0 + 3] = v.w;
        __syncthreads();

        short4 o;
        o.x = (short)f2b(tile[c0 + 0][r]);
        o.y = (short)f2b(tile[c0 + 1][r]);
        o.z = (short)f2b(tile[c0 + 2][r]);
        o.w = (short)f2b(tile[c0 + 3][r]);
        *(short4*)(out + (size_t)(n0 + r) * H_ + k0 + c0) = o;
        return;
    }

    // ---- top-K ----
    const int blk = blockIdx.x - 3072;   // 0..7
    const int b   = blk >> 1;
    const int cls = (blk & 1) ? 2 : 1;
    const int w    = tid >> 6;           // wave 0..3
    const int lane = tid & 63;

    unsigned long long e[8];
    #pragma unroll
    for (int r = 0; r < 8; ++r) {
        int s = w * 512 + lane * 8 + r;  // global token index
        float l0 = logits[(b * S_ + s) * 3 + 0];
        float l1 = logits[(b * S_ + s) * 3 + 1];
        float l2 = logits[(b * S_ + s) * 3 + 2];
        int pred = 0; float bl = l0;
        if (l1 > bl) { bl = l1; pred = 1; }
        if (l2 > bl) { bl = l2; pred = 2; }
        float c = -1.0f;
        if (pred == cls && mask[b * S_ + s] == 1) {
            double m = (double)bl;
            double e0 = exp((double)l0 - m);
            double e1 = exp((double)l1 - m);
            double e2 = exp((double)l2 - m);
            c = (float)(((cls == 1) ? e1 : e2) / (e0 + e1 + e2));
        }
        unsigned int u = __float_as_uint(c);
        unsigned int mono = (u & 0x80000000u) ? ~u : (u | 0x80000000u);
        e[r] = ((unsigned long long)(~mono) << 32) | (unsigned int)s;
    }

    wave_sort512(e, lane);               // ascending: best (highest conf) first

    if (lane < 16) {
        #pragma unroll
        for (int r = 0; r < 8; ++r) cand[w * 128 + lane * 8 + r] = e[r];
    }
    __syncthreads();

    if (w == 0) {
        #pragma unroll
        for (int r = 0; r < 8; ++r) e[r] = cand[lane * 8 + r];
        wave_sort512(e, lane);
        if (lane < 16) {
            int* idx_out = (blk & 1) ? (val_idx + b * KC) : (key_idx + b * KC);
            float* oidx  = out_idx + ((blk & 1) ? B_ * KC : 0) + b * KC;
            #pragma unroll
            for (int r = 0; r < 8; ++r) {
                int sel = (int)(e[r] & 0xffffffffu);
                idx_out[lane * 8 + r] = sel;
                oidx[lane * 8 + r] = (float)sel;
            }
        }
    }
}

// ------------------------------------------------------------------
// Kernel 2: gather seq rows by idx, convert to bf16.
// ------------------------------------------------------------------
__global__ __launch_bounds__(256) void gatherconv_kernel(
    const float* __restrict__ seq,     // [B,S,H]
    const int* __restrict__ key_idx, const int* __restrict__ val_idx,
    unsigned short* __restrict__ Abf)  // [1024][1024]
{
    const int row = blockIdx.x;
    const int tid = threadIdx.x;
    int b, srow;
    if (row < 512) { b = row >> 7; srow = key_idx[row]; }
    else           { b = (row - 512) >> 7; srow = val_idx[row - 512]; }
    const float* src = seq + ((size_t)b * S_ + srow) * H_ + tid * 4;
    float4 v = *(const float4*)src;
    short4 o;
    o.x = (short)f2b(v.x); o.y = (short)f2b(v.y);
    o.z = (short)f2b(v.z); o.w = (short)f2b(v.w);
    *(short4*)(Abf + (size_t)row * H_ + tid * 4) = o;
}

// ------------------------------------------------------------------
// Kernel 3: MFMA GEMM  C[m][n] = A[m][:] . Wt[n][:]  (+bias), bf16->bf16.
// 1 wave per 32x64 tile. z selects {A-slice, Wt, bias}.
// ------------------------------------------------------------------
__global__ __launch_bounds__(64) void gemm_mfma_kernel(
    const unsigned short* __restrict__ A,   // [z*512+512][1024] bf16
    const unsigned short* __restrict__ Wt,  // [z][1024][1024] bf16 (N-major)
    const float* __restrict__ b0, const float* __restrict__ b1,
    unsigned short* __restrict__ Cout)      // [z*512+512][1024] bf16
{
    const int z = blockIdx.z;
    A    += (size_t)z * 512 * H_;
    Wt   += (size_t)z * H_ * H_;
    Cout += (size_t)z * 512 * H_;
    const float* bias = z ? b1 : b0;

    const int l  = threadIdx.x;
    const int m0 = blockIdx.y * 32;
    const int n0 = blockIdx.x * 64;
    const int r  = l & 15;
    const int kb = (l >> 4) * 8;

    f32x4 acc[2][4] = {};
    const unsigned short* a0 = A + (size_t)(m0 + r) * H_ + kb;
    const unsigned short* a1 = a0 + 16 * H_;
    const unsigned short* w0 = Wt + (size_t)(n0 + r) * H_ + kb;

    #pragma unroll 2
    for (int k0 = 0; k0 < H_; k0 += 32) {
        bf16x8 av[2], bv[4];
        av[0] = *(const bf16x8*)(a0 + k0);
        av[1] = *(const bf16x8*)(a1 + k0);
        #pragma unroll
        for (int j = 0; j < 4; ++j)
            bv[j] = *(const bf16x8*)(w0 + (size_t)j * 16 * H_ + k0);
        #pragma unroll
        for (int i = 0; i < 2; ++i)
            #pragma unroll
            for (int j = 0; j < 4; ++j)
                acc[i][j] = __builtin_amdgcn_mfma_f32_16x16x32_bf16(
                    av[i], bv[j], acc[i][j], 0, 0, 0);
    }

    const int orow = (l >> 4) * 4, ocol = l & 15;
    #pragma unroll
    for (int i = 0; i < 2; ++i) {
        #pragma unroll
        for (int j = 0; j < 4; ++j) {
            int n = n0 + j * 16 + ocol;
            float bv_ = bias ? bias[n] : 0.0f;
            #pragma unroll
            for (int g = 0; g < 4; ++g) {
                int m = m0 + i * 16 + orow + g;
                Cout[(size_t)m * H_ + n] = f2b(acc[i][j][g] + bv_);
            }
        }
    }
}

// ------------------------------------------------------------------
// Kernel 4: biaffine via MFMA: scores[b,k,v] = kbt[bk,:].vrep[bv,:] + bbil
// ------------------------------------------------------------------
__global__ __launch_bounds__(64) void biaffine_mfma_kernel(
    const unsigned short* __restrict__ kbt,   // [512][1024] bf16 (b-major)
    const unsigned short* __restrict__ vrep,  // [512][1024] bf16
    const float* __restrict__ bbil,
    float* __restrict__ scores)               // [B,K,V] = d_out
{
    const int b  = blockIdx.z;
    const int l  = threadIdx.x;
    const int m0 = blockIdx.y * 32;
    const int n0 = blockIdx.x * 64;
    const int r  = l & 15;
    const int kb = (l >> 4) * 8;

    f32x4 acc[2][4] = {};
    const unsigned short* a0 = kbt  + (size_t)(b * KC + m0 + r) * H_ + kb;
    const unsigned short* a1 = a0 + 16 * H_;
    const unsigned short* w0 = vrep + (size_t)(b * KC + n0 + r) * H_ + kb;

    #pragma unroll 2
    for (int k0 = 0; k0 < H_; k0 += 32) {
        bf16x8 av[2], bv[4];
        av[0] = *(const bf16x8*)(a0 + k0);
        av[1] = *(const bf16x8*)(a1 + k0);
        #pragma unroll
        for (int j = 0; j < 4; ++j)
            bv[j] = *(const bf16x8*)(w0 + (size_t)j * 16 * H_ + k0);
        #pragma unroll
        for (int i = 0; i < 2; ++i)
            #pragma unroll
            for (int j = 0; j < 4; ++j)
                acc[i][j] = __builtin_amdgcn_mfma_f32_16x16x32_bf16(
                    av[i], bv[j], acc[i][j], 0, 0, 0);
    }

    float bb = *bbil;
    const int orow = (l >> 4) * 4, ocol = l & 15;
    #pragma unroll
    for (int i = 0; i < 2; ++i)
        #pragma unroll
        for (int j = 0; j < 4; ++j)
            #pragma unroll
            for (int g = 0; g < 4; ++g) {
                int m = m0 + i * 16 + orow + g;
                int n = n0 + j * 16 + ocol;
                scores[((size_t)b * KC + m) * KC + n] = acc[i][j][g] + bb;
            }
}

// ------------------------------------------------------------------
// Kernel 5: spatial features + MLP(8->64->32) + final MLP(33->16->1).
// Register-light, in-place on d_out.
// ------------------------------------------------------------------
__global__ __launch_bounds__(128) void fused_spatial_kernel(
    const float* __restrict__ bboxes,  // [B,S,4]
    const int* __restrict__ key_idx, const int* __restrict__ val_idx,
    const float* __restrict__ Ws1, const float* __restrict__ bs1,
    const float* __restrict__ Ws2, const float* __restrict__ bs2,
    const float* __restrict__ Wf1, const float* __restrict__ bf1,
    const float* __restrict__ Wf2, const float* __restrict__ bf2,
    float* sc)                          // [B,K,V] (biaffine in, score out)
{
    __shared__ float sWs1T[64 * 8];
    __shared__ float sbs1[64];
    __shared__ float sWs2[64 * 32];
    __shared__ float sbs2[32];
    __shared__ float sWf1T[16 * 33];
    __shared__ float sbf1[16];
    __shared__ float sWf2[16];

    const int tid = threadIdx.x;
    for (int i = tid; i < 512; i += 128) sWs1T[i] = Ws1[(i & 7) * 64 + (i >> 3)];
    for (int i = tid; i < 64;  i += 128) sbs1[i] = bs1[i];
    for (int i = tid; i < 2048; i += 128) sWs2[i] = Ws2[i];
    for (int i = tid; i < 32;  i += 128) sbs2[i] = bs2[i];
    for (int i = tid; i < 528; i += 128) { int t = i / 33, r = i % 33; sWf1T[i] = Wf1[r * 16 + t]; }
    for (int i = tid; i < 16;  i += 128) sbf1[i] = bf1[i];
    for (int i = tid; i < 16;  i += 128) sWf2[i] = Wf2[i];
    __syncthreads();

    const int gid = blockIdx.x * 128 + tid;   // < 65536
    const int b = gid >> 14;
    const int rem = gid & 16383;
    const int k = rem >> 7;
    const int v = rem & 127;

    const float* kbx = bboxes + ((size_t)b * S_ + key_idx[b * KC + k]) * 4;
    const float* vbx = bboxes + ((size_t)b * S_ + val_idx[b * KC + v]) * 4;
    float k0 = kbx[0], k1 = kbx[1], k2 = kbx[2], k3 = kbx[3];
    float v0 = vbx[0], v1 = vbx[1], v2 = vbx[2], v3 = vbx[3];

    float kcx = (k0 + k2) * 0.5f, kcy = (k1 + k3) * 0.5f;
    float vcx = (v0 + v2) * 0.5f, vcy = (v1 + v3) * 0.5f;
    float dx = vcx - kcx, dy = vcy - kcy;
    float dist = sqrtf(dx * dx + dy * dy + EPSF);
    float angle = atan2f(dy, dx);
    float kh = k3 - k1, vh = v3 - v1, kw = k2 - k0, vw = v2 - v0;
    float h_ov = fmaxf(fminf(k3, v3) - fmaxf(k1, v1), 0.0f);
    float h_align = h_ov / (fminf(kh, vh) + EPSF);
    float v_ov = fmaxf(fminf(k2, v2) - fmaxf(k0, v0), 0.0f);
    float v_align = v_ov / (fminf(kw, vw) + EPSF);
    float area_ratio = (vh * vw) / (kh * kw + EPSF);
    float aspect = (vw / (vh + EPSF)) / (kw / (kh + EPSF));

    float sf[8] = {dx, dy, dist, angle, h_align, v_align, area_ratio, aspect};

    float h2[32];
    #pragma unroll
    for (int t = 0; t < 32; ++t) h2[t] = sbs2[t];

    for (int j = 0; j < 64; ++j) {
        const float* w1 = &sWs1T[j * 8];
        float a = sbs1[j];
        #pragma unroll
        for (int i = 0; i < 8; ++i) a += sf[i] * w1[i];
        a = fmaxf(a, 0.0f);
        const float* w2 = &sWs2[j * 32];
        #pragma unroll
        for (int t = 0; t < 32; ++t) h2[t] += a * w2[t];
    }

    float c0 = sc[gid];
    float score = bf2[0];
    for (int t = 0; t < 16; ++t) {
        const float* w = &sWf1T[t * 33];
        float f = sbf1[t] + c0 * w[0];
        #pragma unroll
        for (int j = 0; j < 32; ++j) f += h2[j] * w[1 + j];
        score += fmaxf(f, 0.0f) * sWf2[t];
    }
    sc[gid] = score;
}

// ------------------------------------------------------------------
extern "C" void kernel_launch(void* const* d_in, const int* in_sizes, int n_in,
                              void* d_out, int out_size, void* d_ws, size_t ws_size,
                              hipStream_t stream) {
    const float* seq    = (const float*)d_in[0];
    const float* logits = (const float*)d_in[1];
    const float* bboxes = (const float*)d_in[2];
    const int*   mask   = (const int*)d_in[3];
    const float* Wk   = (const float*)d_in[4];
    const float* bk   = (const float*)d_in[5];
    const float* Wv   = (const float*)d_in[6];
    const float* bv   = (const float*)d_in[7];
    const float* Wbil = (const float*)d_in[8];
    const float* bbil = (const float*)d_in[9];
    const float* Ws1  = (const float*)d_in[10];
    const float* bs1  = (const float*)d_in[11];
    const float* Ws2  = (const float*)d_in[12];
    const float* bs2  = (const float*)d_in[13];
    const float* Wf1  = (const float*)d_in[14];
    const float* bf1  = (const float*)d_in[15];
    const float* Wf2  = (const float*)d_in[16];
    const float* bf2  = (const float*)d_in[17];

    float* out = (float*)d_out;        // scores [65536] | key_idx | val_idx
    char* ws = (char*)d_ws;

    int* key_idx = (int*)ws;
    int* val_idx = key_idx + B_ * KC;
    unsigned short* Wt   = (unsigned short*)(ws + 4096);
    unsigned short* Abf  = Wt + (size_t)3 * H_ * H_;
    unsigned short* kbt  = Abf;                       // alias (Abf dead by then)
    unsigned short* reps = Abf + (size_t)H_ * H_;
    unsigned short* krep = reps;
    unsigned short* vrep = reps + (size_t)512 * H_;

    prep_kernel<<<3080, 256, 0, stream>>>(Wk, Wv, Wbil, Wt,
                                          logits, mask, key_idx, val_idx,
                                          out + B_ * KC * KC);
    gatherconv_kernel<<<1024, 256, 0, stream>>>(seq, key_idx, val_idx, Abf);

    gemm_mfma_kernel<<<dim3(16, 16, 2), 64, 0, stream>>>(
        Abf, Wt, bk, bv, reps);
    gemm_mfma_kernel<<<dim3(16, 16, 1), 64, 0, stream>>>(
        krep, Wt + (size_t)2 * H_ * H_, nullptr, nullptr, kbt);

    biaffine_mfma_kernel<<<dim3(2, 4, B_), 64, 0, stream>>>(
        kbt, vrep, bbil, out);

    fused_spatial_kernel<<<(B_ * KC * KC) / 128, 128, 0, stream>>>(
        bboxes, key_idx, val_idx,
        Ws1, bs1, Ws2, bs2, Wf1, bf1, Wf2, bf2, out);
}